// Round 7
// baseline (417.426 us; speedup 1.0000x reference)
//
#include <hip/hip_runtime.h>
#include <cstdint>
#include <cstddef>

#define D_MODEL 2048
#define SEQ     2048
#define NB      2
#define ROWS    4096      // NB*SEQ
#define QKV_N   3072      // 2048 + 2*4*128
#define NH      16
#define NKV     4
#define HD      128
#define EPSV    1e-5f
// 1/sqrt(128) * log2(e): folded into Q at RoPE time -> scores arrive in log2 domain
#define QPRE    (0.08838834764831845f * 1.4426950408889634f)

typedef unsigned short ushort_t;
typedef __attribute__((ext_vector_type(8))) short  short8;
typedef __attribute__((ext_vector_type(4))) short  short4v;
typedef __attribute__((ext_vector_type(4))) float  floatx4;

__device__ __forceinline__ ushort_t f2b(float f) {
    unsigned u = __float_as_uint(f);
    u += 0x7fffu + ((u >> 16) & 1u);   // RNE bf16
    return (ushort_t)(u >> 16);
}
__device__ __forceinline__ float b2f(ushort_t u) {
    return __uint_as_float(((unsigned)u) << 16);
}

// pack two f32 -> bf16 pair
__device__ __forceinline__ unsigned pkbf(float lo, float hi) {
    unsigned u0 = __float_as_uint(lo) + 0x8000u;
    unsigned u1 = __float_as_uint(hi) + 0x8000u;
    return __builtin_amdgcn_perm(u1, u0, 0x07060302u);
}

#if __has_builtin(__builtin_amdgcn_mfma_f32_16x16x16bf16_1k)
#define HAVE_1K 1
#endif

__device__ __forceinline__ floatx4 pv_mfma(short4v a, short4v b, floatx4 c) {
#ifdef HAVE_1K
    return __builtin_amdgcn_mfma_f32_16x16x16bf16_1k(a, b, c, 0, 0, 0);
#else
    short8 a8 = {a[0], a[1], a[2], a[3], 0, 0, 0, 0};
    short8 b8 = {b[0], b[1], b[2], b[3], 0, 0, 0, 0};
    return __builtin_amdgcn_mfma_f32_16x16x32_bf16(a8, b8, c, 0, 0, 0);
#endif
}

#define GLD_LDS16(gp, lp) __builtin_amdgcn_global_load_lds( \
    (const __attribute__((address_space(1))) void*)(gp),   \
    (__attribute__((address_space(3))) void*)(lp), 16, 0, 0)

// ---------------- RMSNorm (fp32 in) -> bf16 out -----------------------------
__global__ __launch_bounds__(256) void k_rmsnorm_bf16(
        const float* __restrict__ x, const float* __restrict__ w,
        ushort_t* __restrict__ out) {
    int row = blockIdx.x, t = threadIdx.x;
    const float4* xr = (const float4*)(x + (size_t)row * D_MODEL);
    float4 a = xr[t], b = xr[t + 256];
    float ss = a.x*a.x + a.y*a.y + a.z*a.z + a.w*a.w
             + b.x*b.x + b.y*b.y + b.z*b.z + b.w*b.w;
    for (int m = 1; m < 64; m <<= 1) ss += __shfl_xor(ss, m);
    __shared__ float sred[4];
    if ((t & 63) == 0) sred[t >> 6] = ss;
    __syncthreads();
    float r = rsqrtf((sred[0] + sred[1] + sred[2] + sred[3]) * (1.0f / D_MODEL) + EPSV);
    const float4* wr = (const float4*)w;
    float4 wa = wr[t], wb = wr[t + 256];
    ushort4 pa, pb;
    pa.x = f2b(a.x * r * wa.x); pa.y = f2b(a.y * r * wa.y);
    pa.z = f2b(a.z * r * wa.z); pa.w = f2b(a.w * r * wa.w);
    pb.x = f2b(b.x * r * wb.x); pb.y = f2b(b.y * r * wb.y);
    pb.z = f2b(b.z * r * wb.z); pb.w = f2b(b.w * r * wb.w);
    ushort4* o = (ushort4*)(out + (size_t)row * D_MODEL);
    o[t] = pa; o[t + 256] = pb;
}

// ---------------- RMSNorm (fp32 in) -> fp32 out -----------------------------
__global__ __launch_bounds__(256) void k_rmsnorm_f32(
        const float* __restrict__ x, const float* __restrict__ w,
        float* __restrict__ out) {
    int row = blockIdx.x, t = threadIdx.x;
    const float4* xr = (const float4*)(x + (size_t)row * D_MODEL);
    float4 a = xr[t], b = xr[t + 256];
    float ss = a.x*a.x + a.y*a.y + a.z*a.z + a.w*a.w
             + b.x*b.x + b.y*b.y + b.z*b.z + b.w*b.w;
    for (int m = 1; m < 64; m <<= 1) ss += __shfl_xor(ss, m);
    __shared__ float sred[4];
    if ((t & 63) == 0) sred[t >> 6] = ss;
    __syncthreads();
    float r = rsqrtf((sred[0] + sred[1] + sred[2] + sred[3]) * (1.0f / D_MODEL) + EPSV);
    const float4* wr = (const float4*)w;
    float4 wa = wr[t], wb = wr[t + 256];
    float4 oa, ob;
    oa.x = a.x * r * wa.x; oa.y = a.y * r * wa.y; oa.z = a.z * r * wa.z; oa.w = a.w * r * wa.w;
    ob.x = b.x * r * wb.x; ob.y = b.y * r * wb.y; ob.z = b.z * r * wb.z; ob.w = b.w * r * wb.w;
    float4* o = (float4*)(out + (size_t)row * D_MODEL);
    o[t] = oa; o[t + 256] = ob;
}

// -------- transpose + fp32->bf16: in [R][C] -> out [C][R] -------------------
__global__ __launch_bounds__(256) void k_transpose_cvt(
        const float* __restrict__ in, ushort_t* __restrict__ out, int R, int C) {
    __shared__ float tile[32][33];
    int bc = blockIdx.x * 32, br = blockIdx.y * 32;
    int t = threadIdx.x, lr = t >> 5, lc = t & 31;
    for (int i = 0; i < 4; i++)
        tile[lr + i * 8][lc] = in[(size_t)(br + lr + i * 8) * C + bc + lc];
    __syncthreads();
    for (int i = 0; i < 4; i++)
        out[(size_t)(bc + lr + i * 8) * R + br + lc] = f2b(tile[lc][lr + i * 8]);
}

// -------- GEMM (m97 structure): C[M,N] = A[M,K](bf16)*Bt[N,K](bf16) ---------
// MODE 0: fused QKV epilogue. Each N-tile (128 cols) is exactly one head:
//   heads 0..15 -> Q (clip+RoPE+QPRE -> qrot), 16..19 -> K (clip+RoPE -> krot),
//   20..23 -> V (clip -> transposed into vt). Clipped bf16 tile is bounced
//   through LDS; numerics identical to old qkv-write + k_rope/k_vtrans path
//   (f2b(clip) stored, re-read, rope in f32, f2b out).
// MODE 1: resid add, f32 out (unchanged m97 epilogue).
template <int MODE>
__global__ __launch_bounds__(256) void k_gemm(
        const ushort_t* __restrict__ A, const ushort_t* __restrict__ Bt,
        void* __restrict__ Cout, const float* __restrict__ resid,
        const int* __restrict__ pos_ids, const float* __restrict__ rsin,
        const float* __restrict__ rcos, ushort_t* __restrict__ kout,
        ushort_t* __restrict__ vout, int M, int N, int K) {
    __shared__ __align__(16) ushort_t smem[MODE == 0 ? (128 * 136) : (128 * 64)];
    ushort_t* sA = smem;
    ushort_t* sB = smem + 128 * 32;
    int bm = blockIdx.y * 128, bn = blockIdx.x * 128;
    int t = threadIdx.x;
    int wv = t >> 6, lane = t & 63;
    int wm = (wv >> 1) * 64, wn = (wv & 1) * 64;
    int q4 = lane >> 4, n16 = lane & 15;

    int srow = lane >> 2, scol = (lane & 3) * 8;
    const ushort_t* gA0 = A  + (size_t)(bm + wv * 32 + srow) * K + scol;
    const ushort_t* gA1 = gA0 + (size_t)16 * K;
    const ushort_t* gB0 = Bt + (size_t)(bn + wv * 32 + srow) * K + scol;
    const ushort_t* gB1 = gB0 + (size_t)16 * K;
    ushort_t* lA0 = sA + wv * 1024;
    ushort_t* lA1 = lA0 + 512;
    ushort_t* lB0 = sB + wv * 1024;
    ushort_t* lB1 = lB0 + 512;

    floatx4 zero4 = {0.0f, 0.0f, 0.0f, 0.0f};
    floatx4 acc[4][4];
    for (int i = 0; i < 4; i++)
        for (int j = 0; j < 4; j++) acc[i][j] = zero4;

    for (int k0 = 0; k0 < K; k0 += 32) {
        GLD_LDS16(gA0 + k0, lA0);
        GLD_LDS16(gA1 + k0, lA1);
        GLD_LDS16(gB0 + k0, lB0);
        GLD_LDS16(gB1 + k0, lB1);
        __syncthreads();
        short8 af[4], bfr[4];
        for (int i = 0; i < 4; i++) af[i]  = *(const short8*)&sA[(wm + i * 16 + n16) * 32 + q4 * 8];
        for (int j = 0; j < 4; j++) bfr[j] = *(const short8*)&sB[(wn + j * 16 + n16) * 32 + q4 * 8];
        for (int i = 0; i < 4; i++)
            for (int j = 0; j < 4; j++)
                acc[i][j] = __builtin_amdgcn_mfma_f32_16x16x32_bf16(af[i], bfr[j], acc[i][j], 0, 0, 0);
        __syncthreads();
    }

    if (MODE == 1) {
        for (int i = 0; i < 4; i++) {
            int rbase = bm + wm + i * 16 + q4 * 4;
            for (int j = 0; j < 4; j++) {
                int col = bn + wn + j * 16 + n16;
                float* C = (float*)Cout;
                for (int r = 0; r < 4; r++) {
                    float v = acc[i][j][r] + resid[(size_t)(rbase + r) * N + col];
                    C[(size_t)(rbase + r) * N + col] = v;
                }
            }
        }
        return;
    }

    // ---------------- MODE 0: fused clip + RoPE/scatter or V-transpose ------
    const int TP = 136;                       // padded row (8-elem pad, 272B)
    for (int i = 0; i < 4; i++) {
        int lrow = wm + i * 16 + q4 * 4;
        for (int j = 0; j < 4; j++) {
            int lcol = wn + j * 16 + n16;
            for (int r = 0; r < 4; r++) {
                float v = fminf(fmaxf(acc[i][j][r], -8.0f), 8.0f);
                smem[(lrow + r) * TP + lcol] = f2b(v);
            }
        }
    }
    __syncthreads();

    int head = bn >> 7;                       // 0..23 (= blockIdx.x)
    if (head < 20) {
        // ---- Q or K: RoPE + scatter; 2 threads per row, 32 d each ----
        int lr = t >> 1;                      // local row 0..127
        int row_g = bm + lr;
        int b = row_g >> 11, s = row_g & 2047;
        int pos = pos_ids[row_g];
        int dbase = (t & 1) * 32;
        const float* cp = rcos + (size_t)pos * HD;
        const float* sp = rsin + (size_t)pos * HD;
        float mul = (head < 16) ? QPRE : 1.0f;
        ushort_t* dst;
        if (head < 16)
            dst = (ushort_t*)Cout + ((size_t)(b * NH + head) * SEQ + s) * HD;
        else
            dst = kout + ((size_t)(b * NKV + (head - 16)) * SEQ + s) * HD;
        for (int c = 0; c < 4; c++) {
            int d = dbase + c * 8;
            short8 xl8 = *(const short8*)&smem[lr * TP + d];
            short8 xh8 = *(const short8*)&smem[lr * TP + d + 64];
            float4 cl0 = *(const float4*)(cp + d);
            float4 cl1 = *(const float4*)(cp + d + 4);
            float4 sl0 = *(const float4*)(sp + d);
            float4 sl1 = *(const float4*)(sp + d + 4);
            float4 ch0 = *(const float4*)(cp + d + 64);
            float4 ch1 = *(const float4*)(cp + d + 68);
            float4 sh0 = *(const float4*)(sp + d + 64);
            float4 sh1 = *(const float4*)(sp + d + 68);
            float cl[8] = {cl0.x, cl0.y, cl0.z, cl0.w, cl1.x, cl1.y, cl1.z, cl1.w};
            float sl[8] = {sl0.x, sl0.y, sl0.z, sl0.w, sl1.x, sl1.y, sl1.z, sl1.w};
            float ch[8] = {ch0.x, ch0.y, ch0.z, ch0.w, ch1.x, ch1.y, ch1.z, ch1.w};
            float sh[8] = {sh0.x, sh0.y, sh0.z, sh0.w, sh1.x, sh1.y, sh1.z, sh1.w};
            ushort_t ol[8], oh[8];
            for (int k2 = 0; k2 < 8; k2++) {
                float xl = b2f((ushort_t)xl8[k2]);
                float xh = b2f((ushort_t)xh8[k2]);
                ol[k2] = f2b((xl * cl[k2] - xh * sl[k2]) * mul);
                oh[k2] = f2b((xh * ch[k2] + xl * sh[k2]) * mul);
            }
            uint4 pl, ph;
            pl.x = (unsigned)ol[0] | ((unsigned)ol[1] << 16);
            pl.y = (unsigned)ol[2] | ((unsigned)ol[3] << 16);
            pl.z = (unsigned)ol[4] | ((unsigned)ol[5] << 16);
            pl.w = (unsigned)ol[6] | ((unsigned)ol[7] << 16);
            ph.x = (unsigned)oh[0] | ((unsigned)oh[1] << 16);
            ph.y = (unsigned)oh[2] | ((unsigned)oh[3] << 16);
            ph.z = (unsigned)oh[4] | ((unsigned)oh[5] << 16);
            ph.w = (unsigned)oh[6] | ((unsigned)oh[7] << 16);
            *(uint4*)(dst + d) = pl;
            *(uint4*)(dst + d + 64) = ph;
        }
    } else {
        // ---- V: transpose out of LDS tile -> vt [bh][d][s] ----
        int vslot = head - 20;
        int d = t >> 1;                       // 0..127
        int s0l = (t & 1) * 64;
        int b = bm >> 11;
        int sbase = (bm & 2047) + s0l;
        ushort_t* dst = vout + ((size_t)(b * NKV + vslot) * HD + d) * SEQ + sbase;
        for (int c = 0; c < 8; c++) {
            unsigned v8[8];
            for (int k2 = 0; k2 < 8; k2++)
                v8[k2] = smem[(s0l + c * 8 + k2) * TP + d];
            uint4 w;
            w.x = v8[0] | (v8[1] << 16);
            w.y = v8[2] | (v8[3] << 16);
            w.z = v8[4] | (v8[5] << 16);
            w.w = v8[6] | (v8[7] << 16);
            *(uint4*)(dst + c * 8) = w;
        }
    }
}

// -------- MFMA flash attention v5 (R1-proven, no setprio) -------------------
// Block: 4 waves x 16q = 64 q. Grid: 32 qt x 32 bh = 1024 blocks (LPT desc).
// Byte-identical to the R1 kernel that measured 102.6-103.0us. setprio was
// measured -10% here (R6): waves are barrier-locked per iter -> m190 lockstep
// case, not m191's independent-wave case. Do not re-add.
__global__ __launch_bounds__(256, 2) void k_attn(
        const ushort_t* __restrict__ Q, const ushort_t* __restrict__ Kr,
        const ushort_t* __restrict__ Vt, const int* __restrict__ amask,
        ushort_t* __restrict__ O) {
    int bidx = blockIdx.x;
    int qt = (SEQ / 64 - 1) - (bidx >> 5);    // LPT: long blocks first
    int bh = bidx & 31, h = bh & 15, b = bh >> 4;
    int wave = threadIdx.x >> 6, lane = threadIdx.x & 63;
    int q4 = lane >> 4, n16 = lane & 15;

    __shared__ __align__(16) ushort_t sK[2][64 * 128];   // [kv][d], swizzled
    __shared__ __align__(16) ushort_t sV[2][128 * 64];   // [d][kv], swizzled

    const ushort_t* Qh = Q  + (size_t)bh * SEQ * HD;
    const ushort_t* Kh = Kr + (size_t)(b * NKV + (h >> 2)) * SEQ * HD;
    const ushort_t* Vh = Vt + (size_t)(b * NKV + (h >> 2)) * HD * SEQ;
    const int* am = amask + b * SEQ;

    int q0 = qt * 64 + wave * 16;             // this wave's 16 q cols
    int qcol = q0 + n16;

    short8 qf[4];                              // Q as B-frag: d = kk*32+q4*8+j
    for (int kk = 0; kk < 4; kk++)
        qf[kk] = *(const short8*)(Qh + (size_t)qcol * HD + kk * 32 + q4 * 8);

    floatx4 zero4 = {0.0f, 0.0f, 0.0f, 0.0f};
    floatx4 o_acc[8];                          // O^T[d][q]: d = dt*16+q4*4+r, col q=n16
    for (int dt = 0; dt < 8; dt++) o_acc[dt] = zero4;
    float m_i = -INFINITY, l_i = 0.0f;

    // staging lane geometry (computed once)
    int krow_l = (lane >> 4);                  // + wave*16 + t*4
    int kc_l   = lane & 15;
    int vrow_l = (lane >> 3);                  // + wave*32 + t*8
    int vc_l   = lane & 7;

    auto stage_kv = [&](int buf, int kv0) {
        #pragma unroll
        for (int t = 0; t < 4; t++) {
            int krow = wave * 16 + t * 4 + krow_l;
            int kc   = kc_l ^ (krow & 7);
            GLD_LDS16(Kh + (size_t)(kv0 + krow) * HD + kc * 8,
                      &sK[buf][(wave * 16 + t * 4) * 128]);
            int vrow = wave * 32 + t * 8 + vrow_l;
            int vc   = vc_l ^ (vrow & 7);
            GLD_LDS16(Vh + (size_t)vrow * SEQ + kv0 + vc * 8,
                      &sV[buf][(wave * 32 + t * 8) * 64]);
        }
    };

    int kv_iters = qt + 1;

    // prologue: fill buffer 0, full drain
    stage_kv(0, 0);
    asm volatile("s_waitcnt vmcnt(0)" ::: "memory");
    __builtin_amdgcn_s_barrier();
    __builtin_amdgcn_sched_barrier(0);

    for (int it = 0; it < kv_iters; it++) {
        int cur = it & 1;
        int kv0 = it * 64;
        // issue next tile's loads FIRST -- they stay in flight across all of
        // this iteration's compute; drained only at the bottom vmcnt(0).
        if (it + 1 < kv_iters)
            stage_kv(cur ^ 1, kv0 + 64);

        const ushort_t* sKc = sK[cur];
        const ushort_t* sVc = sV[cur];

        bool tail = (kv0 + 63 > q0);           // wave-uniform causal-mask need
        // ---- S^T = K·Q^T: rows kv = q4*4+r (+jj*16), col q = n16 ----
        floatx4 st[4];
        for (int jj = 0; jj < 4; jj++) st[jj] = zero4;
        for (int jj = 0; jj < 4; jj++) {
            int krow = jj * 16 + n16;
            int sw = krow & 7;
            const ushort_t* kb = sKc + krow * 128;
            for (int kk = 0; kk < 4; kk++) {
                short8 kf = *(const short8*)(kb + ((kk * 4 + q4) ^ sw) * 8);
                st[jj] = __builtin_amdgcn_mfma_f32_16x16x32_bf16(kf, qf[kk], st[jj], 0, 0, 0);
            }
        }
        // ---- mask ----
        for (int jj = 0; jj < 4; jj++) {
            int kvb = kv0 + jj * 16 + q4 * 4;
            int4 am4 = *(const int4*)(am + kvb);
            int amr[4] = {am4.x, am4.y, am4.z, am4.w};
            if (tail) {
                for (int r = 0; r < 4; r++)
                    st[jj][r] = (amr[r] > 0 && kvb + r <= qcol) ? st[jj][r] : -1e30f;
            } else {
                for (int r = 0; r < 4; r++)
                    st[jj][r] = (amr[r] > 0) ? st[jj][r] : -1e30f;
            }
        }
        // ---- online softmax (kv in regs + q4 groups: 2 shuffles per reduce)
        //      T13 deferred rescale: keep old max unless grown by > 8
        //      (log2 domain -> P bounded by 2^8; bf16-safe, f32 accum) ----
        float mx = st[0][0];
        for (int jj = 0; jj < 4; jj++)
            for (int r = 0; r < 4; r++) mx = fmaxf(mx, st[jj][r]);
        mx = fmaxf(mx, __shfl_xor(mx, 16));
        mx = fmaxf(mx, __shfl_xor(mx, 32));
        if (!__all(mx - m_i <= 8.0f)) {
            float mnew = fmaxf(m_i, mx);
            float al = exp2f(m_i - mnew);
            m_i = mnew;
            l_i *= al;
            for (int dt = 0; dt < 8; dt++)
                o_acc[dt] *= al;
        }
        float rs = 0.0f;
        for (int jj = 0; jj < 4; jj++)
            for (int r = 0; r < 4; r++) {
                float p = exp2f(st[jj][r] - m_i);
                st[jj][r] = p;
                rs += p;
            }
        rs += __shfl_xor(rs, 16);
        rs += __shfl_xor(rs, 32);
        l_i += rs;
        // ---- PV: A = V^T frags from LDS (8B), B = P^T from st regs ----
        for (int jj = 0; jj < 4; jj++) {
            union { unsigned u[2]; short4v s; } uu;
            uu.u[0] = pkbf(st[jj][0], st[jj][1]);
            uu.u[1] = pkbf(st[jj][2], st[jj][3]);
            short4v pfr = uu.s;
            int ch = jj * 2 + (q4 >> 1), hh = q4 & 1;
            for (int dt = 0; dt < 8; dt++) {
                int vrow = dt * 16 + n16;
                short4v vf = *(const short4v*)(sVc + vrow * 64 + ((ch ^ (vrow & 7)) * 8) + hh * 4);
                o_acc[dt] = pv_mfma(vf, pfr, o_acc[dt]);
            }
        }
        // ---- single per-iter drain: own prefetch landed + all waves done
        //      reading buf[cur] (their ds_reads were consumed by MFMAs) ----
        asm volatile("s_waitcnt vmcnt(0)" ::: "memory");
        __builtin_amdgcn_s_barrier();
        __builtin_amdgcn_sched_barrier(0);
    }
    // ---- epilogue: O^T lane holds d = dt*16+q4*4+r for col q = n16 ----
    float inv = 1.0f / l_i;
    ushort_t* orow = O + ((size_t)(b * SEQ) + qcol) * D_MODEL + h * HD + q4 * 4;
    for (int dt = 0; dt < 8; dt++) {
        uint2 pk;
        pk.x = pkbf(o_acc[dt][0] * inv, o_acc[dt][1] * inv);
        pk.y = pkbf(o_acc[dt][2] * inv, o_acc[dt][3] * inv);
        *(uint2*)(orow + dt * 16) = pk;
    }
}

// ---------------------------------------------------------------------------
extern "C" void kernel_launch(void* const* d_in, const int* in_sizes, int n_in,
                              void* d_out, int out_size, void* d_ws, size_t ws_size,
                              hipStream_t stream) {
    const float* hidden = (const float*)d_in[0];
    const int*   amask  = (const int*)d_in[1];
    const int*   pos    = (const int*)d_in[2];
    const float* wqkv   = (const float*)d_in[3];
    const float* wout   = (const float*)d_in[4];
    const float* n1w    = (const float*)d_in[5];
    const float* n2w    = (const float*)d_in[6];
    const float* rsin   = (const float*)d_in[7];
    const float* rcos   = (const float*)d_in[8];
    float* out0 = (float*)d_out;
    float* out1 = out0 + (size_t)ROWS * D_MODEL;

    char* ws = (char*)d_ws;
    ushort_t* x_bf    = (ushort_t*)ws;  ws += (size_t)ROWS * D_MODEL * 2;
    ushort_t* wqkv_t  = (ushort_t*)ws;  ws += (size_t)QKV_N * D_MODEL * 2;
    ushort_t* wout_t  = (ushort_t*)ws;  ws += (size_t)D_MODEL * D_MODEL * 2;
    ushort_t* qrot    = (ushort_t*)ws;  ws += (size_t)NB * NH * SEQ * HD * 2;
    ushort_t* krot    = (ushort_t*)ws;  ws += (size_t)NB * NKV * SEQ * HD * 2;
    ushort_t* vt      = (ushort_t*)ws;  ws += (size_t)NB * NKV * HD * SEQ * 2;
    ushort_t* attn    = (ushort_t*)ws;  ws += (size_t)ROWS * D_MODEL * 2;

    k_rmsnorm_bf16<<<ROWS, 256, 0, stream>>>(hidden, n1w, x_bf);
    k_transpose_cvt<<<dim3(QKV_N / 32, D_MODEL / 32), 256, 0, stream>>>(wqkv, wqkv_t, D_MODEL, QKV_N);
    k_transpose_cvt<<<dim3(D_MODEL / 32, D_MODEL / 32), 256, 0, stream>>>(wout, wout_t, D_MODEL, D_MODEL);
    k_gemm<0><<<dim3(QKV_N / 128, ROWS / 128), 256, 0, stream>>>(
        x_bf, wqkv_t, qrot, nullptr, pos, rsin, rcos, krot, vt, ROWS, QKV_N, D_MODEL);
    k_attn<<<(SEQ / 64) * 32, 256, 0, stream>>>(qrot, krot, vt, amask, attn);
    k_gemm<1><<<dim3(D_MODEL / 128, ROWS / 128), 256, 0, stream>>>(
        attn, wout_t, out0, hidden, nullptr, nullptr, nullptr, nullptr, nullptr, ROWS, D_MODEL, D_MODEL);
    k_rmsnorm_f32<<<ROWS, 256, 0, stream>>>(out0, n2w, out1);
}

// Round 8
// 390.091 us; speedup vs baseline: 1.0701x; 1.0701x over previous
//
#include <hip/hip_runtime.h>
#include <cstdint>
#include <cstddef>

#define D_MODEL 2048
#define SEQ     2048
#define NB      2
#define ROWS    4096      // NB*SEQ
#define QKV_N   3072      // 2048 + 2*4*128
#define NH      16
#define NKV     4
#define HD      128
#define EPSV    1e-5f
// 1/sqrt(128) * log2(e): folded into Q at RoPE time -> scores arrive in log2 domain
#define QPRE    (0.08838834764831845f * 1.4426950408889634f)

typedef unsigned short ushort_t;
typedef __attribute__((ext_vector_type(8))) short  short8;
typedef __attribute__((ext_vector_type(4))) short  short4v;
typedef __attribute__((ext_vector_type(4))) float  floatx4;

__device__ __forceinline__ ushort_t f2b(float f) {
    unsigned u = __float_as_uint(f);
    u += 0x7fffu + ((u >> 16) & 1u);   // RNE bf16
    return (ushort_t)(u >> 16);
}
__device__ __forceinline__ float b2f(ushort_t u) {
    return __uint_as_float(((unsigned)u) << 16);
}

// pack two f32 -> bf16 pair
__device__ __forceinline__ unsigned pkbf(float lo, float hi) {
    unsigned u0 = __float_as_uint(lo) + 0x8000u;
    unsigned u1 = __float_as_uint(hi) + 0x8000u;
    return __builtin_amdgcn_perm(u1, u0, 0x07060302u);
}

#if __has_builtin(__builtin_amdgcn_mfma_f32_16x16x16bf16_1k)
#define HAVE_1K 1
#endif

__device__ __forceinline__ floatx4 pv_mfma(short4v a, short4v b, floatx4 c) {
#ifdef HAVE_1K
    return __builtin_amdgcn_mfma_f32_16x16x16bf16_1k(a, b, c, 0, 0, 0);
#else
    short8 a8 = {a[0], a[1], a[2], a[3], 0, 0, 0, 0};
    short8 b8 = {b[0], b[1], b[2], b[3], 0, 0, 0, 0};
    return __builtin_amdgcn_mfma_f32_16x16x32_bf16(a8, b8, c, 0, 0, 0);
#endif
}

#define GLD_LDS16(gp, lp) __builtin_amdgcn_global_load_lds( \
    (const __attribute__((address_space(1))) void*)(gp),   \
    (__attribute__((address_space(3))) void*)(lp), 16, 0, 0)

// ---------------- RMSNorm (fp32 in) -> bf16 out -----------------------------
__global__ __launch_bounds__(256) void k_rmsnorm_bf16(
        const float* __restrict__ x, const float* __restrict__ w,
        ushort_t* __restrict__ out) {
    int row = blockIdx.x, t = threadIdx.x;
    const float4* xr = (const float4*)(x + (size_t)row * D_MODEL);
    float4 a = xr[t], b = xr[t + 256];
    float ss = a.x*a.x + a.y*a.y + a.z*a.z + a.w*a.w
             + b.x*b.x + b.y*b.y + b.z*b.z + b.w*b.w;
    for (int m = 1; m < 64; m <<= 1) ss += __shfl_xor(ss, m);
    __shared__ float sred[4];
    if ((t & 63) == 0) sred[t >> 6] = ss;
    __syncthreads();
    float r = rsqrtf((sred[0] + sred[1] + sred[2] + sred[3]) * (1.0f / D_MODEL) + EPSV);
    const float4* wr = (const float4*)w;
    float4 wa = wr[t], wb = wr[t + 256];
    ushort4 pa, pb;
    pa.x = f2b(a.x * r * wa.x); pa.y = f2b(a.y * r * wa.y);
    pa.z = f2b(a.z * r * wa.z); pa.w = f2b(a.w * r * wa.w);
    pb.x = f2b(b.x * r * wb.x); pb.y = f2b(b.y * r * wb.y);
    pb.z = f2b(b.z * r * wb.z); pb.w = f2b(b.w * r * wb.w);
    ushort4* o = (ushort4*)(out + (size_t)row * D_MODEL);
    o[t] = pa; o[t + 256] = pb;
}

// ---------------- RMSNorm (fp32 in) -> fp32 out -----------------------------
__global__ __launch_bounds__(256) void k_rmsnorm_f32(
        const float* __restrict__ x, const float* __restrict__ w,
        float* __restrict__ out) {
    int row = blockIdx.x, t = threadIdx.x;
    const float4* xr = (const float4*)(x + (size_t)row * D_MODEL);
    float4 a = xr[t], b = xr[t + 256];
    float ss = a.x*a.x + a.y*a.y + a.z*a.z + a.w*a.w
             + b.x*b.x + b.y*b.y + b.z*b.z + b.w*b.w;
    for (int m = 1; m < 64; m <<= 1) ss += __shfl_xor(ss, m);
    __shared__ float sred[4];
    if ((t & 63) == 0) sred[t >> 6] = ss;
    __syncthreads();
    float r = rsqrtf((sred[0] + sred[1] + sred[2] + sred[3]) * (1.0f / D_MODEL) + EPSV);
    const float4* wr = (const float4*)w;
    float4 wa = wr[t], wb = wr[t + 256];
    float4 oa, ob;
    oa.x = a.x * r * wa.x; oa.y = a.y * r * wa.y; oa.z = a.z * r * wa.z; oa.w = a.w * r * wa.w;
    ob.x = b.x * r * wb.x; ob.y = b.y * r * wb.y; ob.z = b.z * r * wb.z; ob.w = b.w * r * wb.w;
    float4* o = (float4*)(out + (size_t)row * D_MODEL);
    o[t] = oa; o[t + 256] = ob;
}

// -------- transpose + fp32->bf16: in [R][C] -> out [C][R] -------------------
__global__ __launch_bounds__(256) void k_transpose_cvt(
        const float* __restrict__ in, ushort_t* __restrict__ out, int R, int C) {
    __shared__ float tile[32][33];
    int bc = blockIdx.x * 32, br = blockIdx.y * 32;
    int t = threadIdx.x, lr = t >> 5, lc = t & 31;
    for (int i = 0; i < 4; i++)
        tile[lr + i * 8][lc] = in[(size_t)(br + lr + i * 8) * C + bc + lc];
    __syncthreads();
    for (int i = 0; i < 4; i++)
        out[(size_t)(bc + lr + i * 8) * R + br + lc] = f2b(tile[lc][lr + i * 8]);
}

// -------- GEMM (m97 structure): C[M,N] = A[M,K](bf16)*Bt[N,K](bf16) ---------
template <int MODE>
__global__ __launch_bounds__(256) void k_gemm(
        const ushort_t* __restrict__ A, const ushort_t* __restrict__ Bt,
        void* __restrict__ Cout, const float* __restrict__ resid,
        int M, int N, int K) {
    __shared__ __align__(16) ushort_t sA[128 * 32];
    __shared__ __align__(16) ushort_t sB[128 * 32];
    int bm = blockIdx.y * 128, bn = blockIdx.x * 128;
    int t = threadIdx.x;
    int wv = t >> 6, lane = t & 63;
    int wm = (wv >> 1) * 64, wn = (wv & 1) * 64;
    int q4 = lane >> 4, n16 = lane & 15;

    int srow = lane >> 2, scol = (lane & 3) * 8;
    const ushort_t* gA0 = A  + (size_t)(bm + wv * 32 + srow) * K + scol;
    const ushort_t* gA1 = gA0 + (size_t)16 * K;
    const ushort_t* gB0 = Bt + (size_t)(bn + wv * 32 + srow) * K + scol;
    const ushort_t* gB1 = gB0 + (size_t)16 * K;
    ushort_t* lA0 = sA + wv * 1024;
    ushort_t* lA1 = lA0 + 512;
    ushort_t* lB0 = sB + wv * 1024;
    ushort_t* lB1 = lB0 + 512;

    floatx4 zero4 = {0.0f, 0.0f, 0.0f, 0.0f};
    floatx4 acc[4][4];
    for (int i = 0; i < 4; i++)
        for (int j = 0; j < 4; j++) acc[i][j] = zero4;

    for (int k0 = 0; k0 < K; k0 += 32) {
        GLD_LDS16(gA0 + k0, lA0);
        GLD_LDS16(gA1 + k0, lA1);
        GLD_LDS16(gB0 + k0, lB0);
        GLD_LDS16(gB1 + k0, lB1);
        __syncthreads();
        short8 af[4], bfr[4];
        for (int i = 0; i < 4; i++) af[i]  = *(const short8*)&sA[(wm + i * 16 + n16) * 32 + q4 * 8];
        for (int j = 0; j < 4; j++) bfr[j] = *(const short8*)&sB[(wn + j * 16 + n16) * 32 + q4 * 8];
        for (int i = 0; i < 4; i++)
            for (int j = 0; j < 4; j++)
                acc[i][j] = __builtin_amdgcn_mfma_f32_16x16x32_bf16(af[i], bfr[j], acc[i][j], 0, 0, 0);
        __syncthreads();
    }

    for (int i = 0; i < 4; i++) {
        int rbase = bm + wm + i * 16 + q4 * 4;
        for (int j = 0; j < 4; j++) {
            int col = bn + wn + j * 16 + n16;
            if (MODE == 0) {
                ushort_t* C = (ushort_t*)Cout;
                for (int r = 0; r < 4; r++) {
                    float v = acc[i][j][r];
                    v = fminf(fmaxf(v, -8.0f), 8.0f);
                    C[(size_t)(rbase + r) * N + col] = f2b(v);
                }
            } else {
                float* C = (float*)Cout;
                for (int r = 0; r < 4; r++) {
                    float v = acc[i][j][r] + resid[(size_t)(rbase + r) * N + col];
                    C[(size_t)(rbase + r) * N + col] = v;
                }
            }
        }
    }
}

// -------- RoPE + scatter; Q pre-scaled by 1/sqrt(d)*log2e -------------------
__global__ __launch_bounds__(256) void k_rope(
        const ushort_t* __restrict__ qkv, const int* __restrict__ pos_ids,
        const float* __restrict__ rsin, const float* __restrict__ rcos,
        ushort_t* __restrict__ qout, ushort_t* __restrict__ kout) {
    int wid  = blockIdx.x * 4 + (threadIdx.x >> 6);
    int lane = threadIdx.x & 63;
    int row = wid / 20, slot = wid - row * 20;
    int b = row >> 11, s = row & 2047;
    int pos = pos_ids[row];
    int col0 = (slot < 16) ? slot * HD : D_MODEL + (slot - 16) * HD;
    const ushort_t* src = qkv + (size_t)row * QKV_N + col0;
    float xl = b2f(src[lane]);
    float xh = b2f(src[lane + 64]);
    const float* cp = rcos + (size_t)pos * HD;
    const float* sp = rsin + (size_t)pos * HD;
    float cl = cp[lane], sl = sp[lane];
    float ch = cp[lane + 64], sh = sp[lane + 64];
    float mul = (slot < 16) ? QPRE : 1.0f;
    float ol = (xl * cl - xh * sl) * mul;
    float oh = (xh * ch + xl * sh) * mul;
    if (slot < 16) {
        size_t dst = ((size_t)(b * NH + slot) * SEQ + s) * HD;
        qout[dst + lane] = f2b(ol); qout[dst + lane + 64] = f2b(oh);
    } else {
        size_t dst = ((size_t)(b * NKV + (slot - 16)) * SEQ + s) * HD;
        kout[dst + lane] = f2b(ol); kout[dst + lane + 64] = f2b(oh);
    }
}

// -------- V transpose: qkv v-slot -> vt [NB,NKV,HD,SEQ] ---------------------
__global__ __launch_bounds__(256) void k_vtrans(
        const ushort_t* __restrict__ qkv, ushort_t* __restrict__ vt) {
    __shared__ ushort_t tile[32][33];
    int bh = blockIdx.z;
    int b = bh >> 2, h = bh & 3;
    int s0 = blockIdx.x * 32, d0 = blockIdx.y * 32;
    int t = threadIdx.x, lr = t >> 5, lc = t & 31;
    int col0 = D_MODEL + NKV * HD + h * HD;
    for (int i = 0; i < 4; i++)
        tile[lr + i * 8][lc] =
            qkv[((size_t)b * SEQ + s0 + lr + i * 8) * QKV_N + col0 + d0 + lc];
    __syncthreads();
    for (int i = 0; i < 4; i++)
        vt[((size_t)bh * HD + d0 + lr + i * 8) * SEQ + s0 + lc] = tile[lc][lr + i * 8];
}

// -------- MFMA flash attention v8: KVBLK=128, single-buffer -----------------
// Block: 4 waves x 16q = 64 q. Grid: 32 qt x 32 bh = 1024 blocks (LPT desc).
// v8 tests the per-iteration-fixed-cost theory: v4 (exposed latency) == v5
// (hidden latency) == 103us proved hiding doesn't matter, so the cost must be
// per-iter FIXED (barrier + drain + staging issue). KVBLK=128 halves the
// number of barrier/drain cycles per kv: stage K[128][128]+Vt[128][128]
// (64KB, single-buffer -> still 2 blocks/CU like every measured variant),
// then run the proven v5 64-kv compute body twice (halves hb=0,1).
__global__ __launch_bounds__(256, 2) void k_attn(
        const ushort_t* __restrict__ Q, const ushort_t* __restrict__ Kr,
        const ushort_t* __restrict__ Vt, const int* __restrict__ amask,
        ushort_t* __restrict__ O) {
    int bidx = blockIdx.x;
    int qt = (SEQ / 64 - 1) - (bidx >> 5);    // LPT: long blocks first
    int bh = bidx & 31, h = bh & 15, b = bh >> 4;
    int wave = threadIdx.x >> 6, lane = threadIdx.x & 63;
    int q4 = lane >> 4, n16 = lane & 15;

    __shared__ __align__(16) ushort_t sK[128 * 128];   // [kv][d], swizzled
    __shared__ __align__(16) ushort_t sV[128 * 128];   // [d][kv], swizzled

    const ushort_t* Qh = Q  + (size_t)bh * SEQ * HD;
    const ushort_t* Kh = Kr + (size_t)(b * NKV + (h >> 2)) * SEQ * HD;
    const ushort_t* Vh = Vt + (size_t)(b * NKV + (h >> 2)) * HD * SEQ;
    const int* am = amask + b * SEQ;

    int q0 = qt * 64 + wave * 16;             // this wave's 16 q cols
    int qcol = q0 + n16;

    short8 qf[4];                              // Q as B-frag: d = kk*32+q4*8+j
    for (int kk = 0; kk < 4; kk++)
        qf[kk] = *(const short8*)(Qh + (size_t)qcol * HD + kk * 32 + q4 * 8);

    floatx4 zero4 = {0.0f, 0.0f, 0.0f, 0.0f};
    floatx4 o_acc[8];                          // O^T[d][q]: d = dt*16+q4*4+r, col q=n16
    for (int dt = 0; dt < 8; dt++) o_acc[dt] = zero4;
    float m_i = -INFINITY, l_i = 0.0f;

    // staging lane geometry: both K and V rows are 256B = 16 x 16B chunks,
    // 16 lanes per row, 4 rows per load, 8 loads per wave per tile half-pair
    int row_l = lane >> 4;                     // + wave*32 + t*4
    int c16   = lane & 15;                     // 16B chunk within row

    int kv_iters = (qt >> 1) + 1;              // 128-kv tiles

    for (int it = 0; it < kv_iters; it++) {
        int kv0 = it * 128;
        __syncthreads();                       // prior tile's LDS reads done
        #pragma unroll
        for (int t = 0; t < 8; t++) {
            int krow = wave * 32 + t * 4 + row_l;        // K: kv row 0..127
            int kc   = c16 ^ (krow & 7);                 // swizzle low 3 bits
            GLD_LDS16(Kh + (size_t)(kv0 + krow) * HD + kc * 8,
                      sK + (wave * 32 + t * 4) * 128);
            int vrow = wave * 32 + t * 4 + row_l;        // V^T: d row 0..127
            int vc   = (c16 & 8) | ((c16 & 7) ^ (vrow & 7)); // swizzle per 64-half
            GLD_LDS16(Vh + (size_t)vrow * SEQ + kv0 + vc * 8,
                      sV + (wave * 32 + t * 4) * 128);
        }
        asm volatile("s_waitcnt vmcnt(0)" ::: "memory");
        __builtin_amdgcn_s_barrier();          // staging visible
        __builtin_amdgcn_sched_barrier(0);

        #pragma unroll
        for (int hb = 0; hb < 2; hb++) {
            int kvbase = kv0 + hb * 64;
            if (kvbase > qt * 64 + 63) break;  // block-uniform causal skip
            bool tail = (kvbase + 63 > q0);    // wave-uniform tail-mask need
            // ---- S^T = K·Q^T: rows kv = q4*4+r (+jj*16), col q = n16 ----
            floatx4 st[4];
            for (int jj = 0; jj < 4; jj++) st[jj] = zero4;
            for (int jj = 0; jj < 4; jj++) {
                int krow = hb * 64 + jj * 16 + n16;
                int sw = krow & 7;
                const ushort_t* kb = sK + krow * 128;
                for (int kk = 0; kk < 4; kk++) {
                    short8 kf = *(const short8*)(kb + ((kk * 4 + q4) ^ sw) * 8);
                    st[jj] = __builtin_amdgcn_mfma_f32_16x16x32_bf16(kf, qf[kk], st[jj], 0, 0, 0);
                }
            }
            // ---- mask ----
            for (int jj = 0; jj < 4; jj++) {
                int kvb = kvbase + jj * 16 + q4 * 4;
                int4 am4 = *(const int4*)(am + kvb);
                int amr[4] = {am4.x, am4.y, am4.z, am4.w};
                if (tail) {
                    for (int r = 0; r < 4; r++)
                        st[jj][r] = (amr[r] > 0 && kvb + r <= qcol) ? st[jj][r] : -1e30f;
                } else {
                    for (int r = 0; r < 4; r++)
                        st[jj][r] = (amr[r] > 0) ? st[jj][r] : -1e30f;
                }
            }
            // ---- online softmax (kv in regs + q4 groups: 2 shuffles/reduce)
            //      T13 deferred rescale (log2 domain, THR=8) ----
            float mx = st[0][0];
            for (int jj = 0; jj < 4; jj++)
                for (int r = 0; r < 4; r++) mx = fmaxf(mx, st[jj][r]);
            mx = fmaxf(mx, __shfl_xor(mx, 16));
            mx = fmaxf(mx, __shfl_xor(mx, 32));
            if (!__all(mx - m_i <= 8.0f)) {
                float mnew = fmaxf(m_i, mx);
                float al = exp2f(m_i - mnew);
                m_i = mnew;
                l_i *= al;
                for (int dt = 0; dt < 8; dt++)
                    o_acc[dt] *= al;
            }
            float rs = 0.0f;
            for (int jj = 0; jj < 4; jj++)
                for (int r = 0; r < 4; r++) {
                    float p = exp2f(st[jj][r] - m_i);
                    st[jj][r] = p;
                    rs += p;
                }
            rs += __shfl_xor(rs, 16);
            rs += __shfl_xor(rs, 32);
            l_i += rs;
            // ---- PV: A = V^T frags from LDS (8B), B = P^T from st regs ----
            for (int jj = 0; jj < 4; jj++) {
                union { unsigned u[2]; short4v s; } uu;
                uu.u[0] = pkbf(st[jj][0], st[jj][1]);
                uu.u[1] = pkbf(st[jj][2], st[jj][3]);
                short4v pfr = uu.s;
                int ch = jj * 2 + (q4 >> 1), hh = q4 & 1;
                for (int dt = 0; dt < 8; dt++) {
                    int vrow = dt * 16 + n16;
                    short4v vf = *(const short4v*)(sV + vrow * 128 + hb * 64 +
                                                   ((ch ^ (vrow & 7)) * 8) + hh * 4);
                    o_acc[dt] = pv_mfma(vf, pfr, o_acc[dt]);
                }
            }
        }
    }
    // ---- epilogue: O^T lane holds d = dt*16+q4*4+r for col q = n16 ----
    float inv = 1.0f / l_i;
    ushort_t* orow = O + ((size_t)(b * SEQ) + qcol) * D_MODEL + h * HD + q4 * 4;
    for (int dt = 0; dt < 8; dt++) {
        uint2 pk;
        pk.x = pkbf(o_acc[dt][0] * inv, o_acc[dt][1] * inv);
        pk.y = pkbf(o_acc[dt][2] * inv, o_acc[dt][3] * inv);
        *(uint2*)(orow + dt * 16) = pk;
    }
}

// ---------------------------------------------------------------------------
extern "C" void kernel_launch(void* const* d_in, const int* in_sizes, int n_in,
                              void* d_out, int out_size, void* d_ws, size_t ws_size,
                              hipStream_t stream) {
    const float* hidden = (const float*)d_in[0];
    const int*   amask  = (const int*)d_in[1];
    const int*   pos    = (const int*)d_in[2];
    const float* wqkv   = (const float*)d_in[3];
    const float* wout   = (const float*)d_in[4];
    const float* n1w    = (const float*)d_in[5];
    const float* n2w    = (const float*)d_in[6];
    const float* rsin   = (const float*)d_in[7];
    const float* rcos   = (const float*)d_in[8];
    float* out0 = (float*)d_out;
    float* out1 = out0 + (size_t)ROWS * D_MODEL;

    char* ws = (char*)d_ws;
    ushort_t* x_bf    = (ushort_t*)ws;  ws += (size_t)ROWS * D_MODEL * 2;
    ushort_t* wqkv_t  = (ushort_t*)ws;  ws += (size_t)QKV_N * D_MODEL * 2;
    ushort_t* wout_t  = (ushort_t*)ws;  ws += (size_t)D_MODEL * D_MODEL * 2;
    ushort_t* qkv     = (ushort_t*)ws;  ws += (size_t)ROWS * QKV_N * 2;
    ushort_t* qrot    = (ushort_t*)ws;  ws += (size_t)NB * NH * SEQ * HD * 2;
    ushort_t* krot    = (ushort_t*)ws;  ws += (size_t)NB * NKV * SEQ * HD * 2;
    ushort_t* vt      = (ushort_t*)ws;  ws += (size_t)NB * NKV * HD * SEQ * 2;
    ushort_t* attn    = (ushort_t*)ws;  ws += (size_t)ROWS * D_MODEL * 2;

    k_rmsnorm_bf16<<<ROWS, 256, 0, stream>>>(hidden, n1w, x_bf);
    k_transpose_cvt<<<dim3(QKV_N / 32, D_MODEL / 32), 256, 0, stream>>>(wqkv, wqkv_t, D_MODEL, QKV_N);
    k_transpose_cvt<<<dim3(D_MODEL / 32, D_MODEL / 32), 256, 0, stream>>>(wout, wout_t, D_MODEL, D_MODEL);
    k_gemm<0><<<dim3(QKV_N / 128, ROWS / 128), 256, 0, stream>>>(x_bf, wqkv_t, qkv, nullptr, ROWS, QKV_N, D_MODEL);
    k_rope<<<ROWS * 20 / 4, 256, 0, stream>>>(qkv, pos, rsin, rcos, qrot, krot);
    k_vtrans<<<dim3(SEQ / 32, HD / 32, NB * NKV), 256, 0, stream>>>(qkv, vt);
    k_attn<<<(SEQ / 64) * 32, 256, 0, stream>>>(qrot, krot, vt, amask, attn);
    k_gemm<1><<<dim3(D_MODEL / 128, ROWS / 128), 256, 0, stream>>>(attn, wout_t, out0, hidden, ROWS, D_MODEL, D_MODEL);
    k_rmsnorm_f32<<<ROWS, 256, 0, stream>>>(out0, n2w, out1);
}

// Round 10
// 379.650 us; speedup vs baseline: 1.0995x; 1.0275x over previous
//
#include <hip/hip_runtime.h>
#include <cstdint>
#include <cstddef>

#define D_MODEL 2048
#define SEQ     2048
#define NB      2
#define ROWS    4096      // NB*SEQ
#define QKV_N   3072      // 2048 + 2*4*128
#define NH      16
#define NKV     4
#define HD      128
#define EPSV    1e-5f
// 1/sqrt(128) * log2(e): folded into Q at RoPE time -> scores arrive in log2 domain
#define QPRE    (0.08838834764831845f * 1.4426950408889634f)

typedef unsigned short ushort_t;
typedef __attribute__((ext_vector_type(8))) short  short8;
typedef __attribute__((ext_vector_type(4))) short  short4v;
typedef __attribute__((ext_vector_type(4))) float  floatx4;

__device__ __forceinline__ ushort_t f2b(float f) {
    unsigned u = __float_as_uint(f);
    u += 0x7fffu + ((u >> 16) & 1u);   // RNE bf16
    return (ushort_t)(u >> 16);
}
__device__ __forceinline__ float b2f(ushort_t u) {
    return __uint_as_float(((unsigned)u) << 16);
}

// pack two f32 -> bf16 pair
__device__ __forceinline__ unsigned pkbf(float lo, float hi) {
    unsigned u0 = __float_as_uint(lo) + 0x8000u;
    unsigned u1 = __float_as_uint(hi) + 0x8000u;
    return __builtin_amdgcn_perm(u1, u0, 0x07060302u);
}

#if __has_builtin(__builtin_amdgcn_mfma_f32_16x16x16bf16_1k)
#define HAVE_1K 1
#endif

__device__ __forceinline__ floatx4 pv_mfma(short4v a, short4v b, floatx4 c) {
#ifdef HAVE_1K
    return __builtin_amdgcn_mfma_f32_16x16x16bf16_1k(a, b, c, 0, 0, 0);
#else
    short8 a8 = {a[0], a[1], a[2], a[3], 0, 0, 0, 0};
    short8 b8 = {b[0], b[1], b[2], b[3], 0, 0, 0, 0};
    return __builtin_amdgcn_mfma_f32_16x16x32_bf16(a8, b8, c, 0, 0, 0);
#endif
}

#define GLD_LDS16(gp, lp) __builtin_amdgcn_global_load_lds( \
    (const __attribute__((address_space(1))) void*)(gp),   \
    (__attribute__((address_space(3))) void*)(lp), 16, 0, 0)

// ---------------- RMSNorm (fp32 in) -> bf16 out -----------------------------
__global__ __launch_bounds__(256) void k_rmsnorm_bf16(
        const float* __restrict__ x, const float* __restrict__ w,
        ushort_t* __restrict__ out) {
    int row = blockIdx.x, t = threadIdx.x;
    const float4* xr = (const float4*)(x + (size_t)row * D_MODEL);
    float4 a = xr[t], b = xr[t + 256];
    float ss = a.x*a.x + a.y*a.y + a.z*a.z + a.w*a.w
             + b.x*b.x + b.y*b.y + b.z*b.z + b.w*b.w;
    for (int m = 1; m < 64; m <<= 1) ss += __shfl_xor(ss, m);
    __shared__ float sred[4];
    if ((t & 63) == 0) sred[t >> 6] = ss;
    __syncthreads();
    float r = rsqrtf((sred[0] + sred[1] + sred[2] + sred[3]) * (1.0f / D_MODEL) + EPSV);
    const float4* wr = (const float4*)w;
    float4 wa = wr[t], wb = wr[t + 256];
    ushort4 pa, pb;
    pa.x = f2b(a.x * r * wa.x); pa.y = f2b(a.y * r * wa.y);
    pa.z = f2b(a.z * r * wa.z); pa.w = f2b(a.w * r * wa.w);
    pb.x = f2b(b.x * r * wb.x); pb.y = f2b(b.y * r * wb.y);
    pb.z = f2b(b.z * r * wb.z); pb.w = f2b(b.w * r * wb.w);
    ushort4* o = (ushort4*)(out + (size_t)row * D_MODEL);
    o[t] = pa; o[t + 256] = pb;
}

// ---------------- RMSNorm (fp32 in) -> fp32 out -----------------------------
__global__ __launch_bounds__(256) void k_rmsnorm_f32(
        const float* __restrict__ x, const float* __restrict__ w,
        float* __restrict__ out) {
    int row = blockIdx.x, t = threadIdx.x;
    const float4* xr = (const float4*)(x + (size_t)row * D_MODEL);
    float4 a = xr[t], b = xr[t + 256];
    float ss = a.x*a.x + a.y*a.y + a.z*a.z + a.w*a.w
             + b.x*b.x + b.y*b.y + b.z*b.z + b.w*b.w;
    for (int m = 1; m < 64; m <<= 1) ss += __shfl_xor(ss, m);
    __shared__ float sred[4];
    if ((t & 63) == 0) sred[t >> 6] = ss;
    __syncthreads();
    float r = rsqrtf((sred[0] + sred[1] + sred[2] + sred[3]) * (1.0f / D_MODEL) + EPSV);
    const float4* wr = (const float4*)w;
    float4 wa = wr[t], wb = wr[t + 256];
    float4 oa, ob;
    oa.x = a.x * r * wa.x; oa.y = a.y * r * wa.y; oa.z = a.z * r * wa.z; oa.w = a.w * r * wa.w;
    ob.x = b.x * r * wb.x; ob.y = b.y * r * wb.y; ob.z = b.z * r * wb.z; ob.w = b.w * r * wb.w;
    float4* o = (float4*)(out + (size_t)row * D_MODEL);
    o[t] = oa; o[t + 256] = ob;
}

// -------- transpose + fp32->bf16: in [R][C] -> out [C][R] -------------------
__global__ __launch_bounds__(256) void k_transpose_cvt(
        const float* __restrict__ in, ushort_t* __restrict__ out, int R, int C) {
    __shared__ float tile[32][33];
    int bc = blockIdx.x * 32, br = blockIdx.y * 32;
    int t = threadIdx.x, lr = t >> 5, lc = t & 31;
    for (int i = 0; i < 4; i++)
        tile[lr + i * 8][lc] = in[(size_t)(br + lr + i * 8) * C + bc + lc];
    __syncthreads();
    for (int i = 0; i < 4; i++)
        out[(size_t)(bc + lr + i * 8) * R + br + lc] = f2b(tile[lc][lr + i * 8]);
}

// -------- GEMM v2 (m97 structure, BK=64): C = A[M,K](bf16)*Bt[N,K](bf16) ----
// BK=32 -> 64: halves the per-K-step vmcnt(0)+barrier drain count (the
// documented ~20-45% m97 stall) at K=2048 (64 -> 32 iters). LDS 16 -> 32 KB
// keeps ~4 blocks/CU (m132's BK=128/64KB regression avoided). 128B rows would
// be a 16-way read conflict if linear -> XOR-swizzle via pre-swizzled global
// source (same involution on store-src and read, attn-proven pattern):
//   LDS[row][c] holds global chunk c ^ (row&7); read chunk g at c = g^(row&7).
template <int MODE>
__global__ __launch_bounds__(256) void k_gemm(
        const ushort_t* __restrict__ A, const ushort_t* __restrict__ Bt,
        void* __restrict__ Cout, const float* __restrict__ resid,
        int M, int N, int K) {
    __shared__ __align__(16) ushort_t sA[128 * 64];
    __shared__ __align__(16) ushort_t sB[128 * 64];
    int bm = blockIdx.y * 128, bn = blockIdx.x * 128;
    int t = threadIdx.x;
    int wv = t >> 6, lane = t & 63;
    int wm = (wv >> 1) * 64, wn = (wv & 1) * 64;
    int q4 = lane >> 4, n16 = lane & 15;

    // staging: 8 lanes/row, 8 rows per load-inst per wave; 4 insts cover the
    // wave's 32 rows of each matrix. Pre-swizzled source chunk:
    // row_local & 7 == lane>>3 (i*8 and wv*32 are multiples of 8).
    int srow8 = lane >> 3;                     // 0..7
    int sxor  = ((lane & 7) ^ srow8) * 8;      // swizzled 16B-chunk offset
    const ushort_t* gA = A  + (size_t)(bm + wv * 32 + srow8) * K + sxor;
    const ushort_t* gB = Bt + (size_t)(bn + wv * 32 + srow8) * K + sxor;
    ushort_t* lA = sA + wv * 32 * 64;
    ushort_t* lB = sB + wv * 32 * 64;

    floatx4 zero4 = {0.0f, 0.0f, 0.0f, 0.0f};
    floatx4 acc[4][4];
    for (int i = 0; i < 4; i++)
        for (int j = 0; j < 4; j++) acc[i][j] = zero4;

    for (int k0 = 0; k0 < K; k0 += 64) {
        #pragma unroll
        for (int i = 0; i < 4; i++) {
            GLD_LDS16(gA + (size_t)(i * 8) * K + k0, lA + i * 8 * 64);
            GLD_LDS16(gB + (size_t)(i * 8) * K + k0, lB + i * 8 * 64);
        }
        __syncthreads();
        #pragma unroll
        for (int kk = 0; kk < 2; kk++) {
            short8 af[4], bfr[4];
            for (int i = 0; i < 4; i++) {
                int row = wm + i * 16 + n16;
                af[i]  = *(const short8*)&sA[row * 64 + (((kk * 4 + q4) ^ (row & 7)) * 8)];
            }
            for (int j = 0; j < 4; j++) {
                int row = wn + j * 16 + n16;
                bfr[j] = *(const short8*)&sB[row * 64 + (((kk * 4 + q4) ^ (row & 7)) * 8)];
            }
            for (int i = 0; i < 4; i++)
                for (int j = 0; j < 4; j++)
                    acc[i][j] = __builtin_amdgcn_mfma_f32_16x16x32_bf16(af[i], bfr[j], acc[i][j], 0, 0, 0);
        }
        __syncthreads();
    }

    for (int i = 0; i < 4; i++) {
        int rbase = bm + wm + i * 16 + q4 * 4;
        for (int j = 0; j < 4; j++) {
            int col = bn + wn + j * 16 + n16;
            if (MODE == 0) {
                ushort_t* C = (ushort_t*)Cout;
                for (int r = 0; r < 4; r++) {
                    float v = acc[i][j][r];
                    v = fminf(fmaxf(v, -8.0f), 8.0f);
                    C[(size_t)(rbase + r) * N + col] = f2b(v);
                }
            } else {
                float* C = (float*)Cout;
                for (int r = 0; r < 4; r++) {
                    float v = acc[i][j][r] + resid[(size_t)(rbase + r) * N + col];
                    C[(size_t)(rbase + r) * N + col] = v;
                }
            }
        }
    }
}

// -------- RoPE + scatter; Q pre-scaled by 1/sqrt(d)*log2e -------------------
__global__ __launch_bounds__(256) void k_rope(
        const ushort_t* __restrict__ qkv, const int* __restrict__ pos_ids,
        const float* __restrict__ rsin, const float* __restrict__ rcos,
        ushort_t* __restrict__ qout, ushort_t* __restrict__ kout) {
    int wid  = blockIdx.x * 4 + (threadIdx.x >> 6);
    int lane = threadIdx.x & 63;
    int row = wid / 20, slot = wid - row * 20;
    int b = row >> 11, s = row & 2047;
    int pos = pos_ids[row];
    int col0 = (slot < 16) ? slot * HD : D_MODEL + (slot - 16) * HD;
    const ushort_t* src = qkv + (size_t)row * QKV_N + col0;
    float xl = b2f(src[lane]);
    float xh = b2f(src[lane + 64]);
    const float* cp = rcos + (size_t)pos * HD;
    const float* sp = rsin + (size_t)pos * HD;
    float cl = cp[lane], sl = sp[lane];
    float ch = cp[lane + 64], sh = sp[lane + 64];
    float mul = (slot < 16) ? QPRE : 1.0f;
    float ol = (xl * cl - xh * sl) * mul;
    float oh = (xh * ch + xl * sh) * mul;
    if (slot < 16) {
        size_t dst = ((size_t)(b * NH + slot) * SEQ + s) * HD;
        qout[dst + lane] = f2b(ol); qout[dst + lane + 64] = f2b(oh);
    } else {
        size_t dst = ((size_t)(b * NKV + (slot - 16)) * SEQ + s) * HD;
        kout[dst + lane] = f2b(ol); kout[dst + lane + 64] = f2b(oh);
    }
}

// -------- V transpose: qkv v-slot -> vt [NB,NKV,HD,SEQ] ---------------------
__global__ __launch_bounds__(256) void k_vtrans(
        const ushort_t* __restrict__ qkv, ushort_t* __restrict__ vt) {
    __shared__ ushort_t tile[32][33];
    int bh = blockIdx.z;
    int b = bh >> 2, h = bh & 3;
    int s0 = blockIdx.x * 32, d0 = blockIdx.y * 32;
    int t = threadIdx.x, lr = t >> 5, lc = t & 31;
    int col0 = D_MODEL + NKV * HD + h * HD;
    for (int i = 0; i < 4; i++)
        tile[lr + i * 8][lc] =
            qkv[((size_t)b * SEQ + s0 + lr + i * 8) * QKV_N + col0 + d0 + lc];
    __syncthreads();
    for (int i = 0; i < 4; i++)
        vt[((size_t)bh * HD + d0 + lr + i * 8) * SEQ + s0 + lc] = tile[lc][lr + i * 8];
}

// -------- MFMA flash attention v5 (R1-proven best: 102.6us) -----------------
// Block: 4 waves x 16q = 64 q. Grid: 32 qt x 32 bh = 1024 blocks (LPT desc).
// Six structural variants (occupancy, buffering, LDS traffic, TLP, barrier
// frequency) all froze at 103-113us -> this family's minimum is v5. Do not
// re-probe; only the m214 32x32/8-warp rewrite could move it.
__global__ __launch_bounds__(256, 2) void k_attn(
        const ushort_t* __restrict__ Q, const ushort_t* __restrict__ Kr,
        const ushort_t* __restrict__ Vt, const int* __restrict__ amask,
        ushort_t* __restrict__ O) {
    int bidx = blockIdx.x;
    int qt = (SEQ / 64 - 1) - (bidx >> 5);    // LPT: long blocks first
    int bh = bidx & 31, h = bh & 15, b = bh >> 4;
    int wave = threadIdx.x >> 6, lane = threadIdx.x & 63;
    int q4 = lane >> 4, n16 = lane & 15;

    __shared__ __align__(16) ushort_t sK[2][64 * 128];   // [kv][d], swizzled
    __shared__ __align__(16) ushort_t sV[2][128 * 64];   // [d][kv], swizzled

    const ushort_t* Qh = Q  + (size_t)bh * SEQ * HD;
    const ushort_t* Kh = Kr + (size_t)(b * NKV + (h >> 2)) * SEQ * HD;
    const ushort_t* Vh = Vt + (size_t)(b * NKV + (h >> 2)) * HD * SEQ;
    const int* am = amask + b * SEQ;

    int q0 = qt * 64 + wave * 16;             // this wave's 16 q cols
    int qcol = q0 + n16;

    short8 qf[4];                              // Q as B-frag: d = kk*32+q4*8+j
    for (int kk = 0; kk < 4; kk++)
        qf[kk] = *(const short8*)(Qh + (size_t)qcol * HD + kk * 32 + q4 * 8);

    floatx4 zero4 = {0.0f, 0.0f, 0.0f, 0.0f};
    floatx4 o_acc[8];                          // O^T[d][q]: d = dt*16+q4*4+r, col q=n16
    for (int dt = 0; dt < 8; dt++) o_acc[dt] = zero4;
    float m_i = -INFINITY, l_i = 0.0f;

    // staging lane geometry (computed once)
    int krow_l = (lane >> 4);                  // + wave*16 + t*4
    int kc_l   = lane & 15;
    int vrow_l = (lane >> 3);                  // + wave*32 + t*8
    int vc_l   = lane & 7;

    auto stage_kv = [&](int buf, int kv0) {
        #pragma unroll
        for (int t = 0; t < 4; t++) {
            int krow = wave * 16 + t * 4 + krow_l;
            int kc   = kc_l ^ (krow & 7);
            GLD_LDS16(Kh + (size_t)(kv0 + krow) * HD + kc * 8,
                      &sK[buf][(wave * 16 + t * 4) * 128]);
            int vrow = wave * 32 + t * 8 + vrow_l;
            int vc   = vc_l ^ (vrow & 7);
            GLD_LDS16(Vh + (size_t)vrow * SEQ + kv0 + vc * 8,
                      &sV[buf][(wave * 32 + t * 8) * 64]);
        }
    };

    int kv_iters = qt + 1;

    // prologue: fill buffer 0, full drain
    stage_kv(0, 0);
    asm volatile("s_waitcnt vmcnt(0)" ::: "memory");
    __builtin_amdgcn_s_barrier();
    __builtin_amdgcn_sched_barrier(0);

    for (int it = 0; it < kv_iters; it++) {
        int cur = it & 1;
        int kv0 = it * 64;
        // issue next tile's loads FIRST -- they stay in flight across all of
        // this iteration's compute; drained only at the bottom vmcnt(0).
        if (it + 1 < kv_iters)
            stage_kv(cur ^ 1, kv0 + 64);

        const ushort_t* sKc = sK[cur];
        const ushort_t* sVc = sV[cur];

        bool tail = (kv0 + 63 > q0);           // wave-uniform causal-mask need
        // ---- S^T = K·Q^T: rows kv = q4*4+r (+jj*16), col q = n16 ----
        floatx4 st[4];
        for (int jj = 0; jj < 4; jj++) st[jj] = zero4;
        for (int jj = 0; jj < 4; jj++) {
            int krow = jj * 16 + n16;
            int sw = krow & 7;
            const ushort_t* kb = sKc + krow * 128;
            for (int kk = 0; kk < 4; kk++) {
                short8 kf = *(const short8*)(kb + ((kk * 4 + q4) ^ sw) * 8);
                st[jj] = __builtin_amdgcn_mfma_f32_16x16x32_bf16(kf, qf[kk], st[jj], 0, 0, 0);
            }
        }
        // ---- mask ----
        for (int jj = 0; jj < 4; jj++) {
            int kvb = kv0 + jj * 16 + q4 * 4;
            int4 am4 = *(const int4*)(am + kvb);
            int amr[4] = {am4.x, am4.y, am4.z, am4.w};
            if (tail) {
                for (int r = 0; r < 4; r++)
                    st[jj][r] = (amr[r] > 0 && kvb + r <= qcol) ? st[jj][r] : -1e30f;
            } else {
                for (int r = 0; r < 4; r++)
                    st[jj][r] = (amr[r] > 0) ? st[jj][r] : -1e30f;
            }
        }
        // ---- online softmax (kv in regs + q4 groups: 2 shuffles per reduce)
        //      T13 deferred rescale: keep old max unless grown by > 8
        //      (log2 domain -> P bounded by 2^8; bf16-safe, f32 accum) ----
        float mx = st[0][0];
        for (int jj = 0; jj < 4; jj++)
            for (int r = 0; r < 4; r++) mx = fmaxf(mx, st[jj][r]);
        mx = fmaxf(mx, __shfl_xor(mx, 16));
        mx = fmaxf(mx, __shfl_xor(mx, 32));
        if (!__all(mx - m_i <= 8.0f)) {
            float mnew = fmaxf(m_i, mx);
            float al = exp2f(m_i - mnew);
            m_i = mnew;
            l_i *= al;
            for (int dt = 0; dt < 8; dt++)
                o_acc[dt] *= al;
        }
        float rs = 0.0f;
        for (int jj = 0; jj < 4; jj++)
            for (int r = 0; r < 4; r++) {
                float p = exp2f(st[jj][r] - m_i);
                st[jj][r] = p;
                rs += p;
            }
        rs += __shfl_xor(rs, 16);
        rs += __shfl_xor(rs, 32);
        l_i += rs;
        // ---- PV: A = V^T frags from LDS (8B), B = P^T from st regs ----
        for (int jj = 0; jj < 4; jj++) {
            union { unsigned u[2]; short4v s; } uu;
            uu.u[0] = pkbf(st[jj][0], st[jj][1]);
            uu.u[1] = pkbf(st[jj][2], st[jj][3]);
            short4v pfr = uu.s;
            int ch = jj * 2 + (q4 >> 1), hh = q4 & 1;
            for (int dt = 0; dt < 8; dt++) {
                int vrow = dt * 16 + n16;
                short4v vf = *(const short4v*)(sVc + vrow * 64 + ((ch ^ (vrow & 7)) * 8) + hh * 4);
                o_acc[dt] = pv_mfma(vf, pfr, o_acc[dt]);
            }
        }
        // ---- single per-iter drain: own prefetch landed + all waves done
        //      reading buf[cur] (their ds_reads were consumed by MFMAs) ----
        asm volatile("s_waitcnt vmcnt(0)" ::: "memory");
        __builtin_amdgcn_s_barrier();
        __builtin_amdgcn_sched_barrier(0);
    }
    // ---- epilogue: O^T lane holds d = dt*16+q4*4+r for col q = n16 ----
    float inv = 1.0f / l_i;
    ushort_t* orow = O + ((size_t)(b * SEQ) + qcol) * D_MODEL + h * HD + q4 * 4;
    for (int dt = 0; dt < 8; dt++) {
        uint2 pk;
        pk.x = pkbf(o_acc[dt][0] * inv, o_acc[dt][1] * inv);
        pk.y = pkbf(o_acc[dt][2] * inv, o_acc[dt][3] * inv);
        *(uint2*)(orow + dt * 16) = pk;
    }
}

// ---------------------------------------------------------------------------
extern "C" void kernel_launch(void* const* d_in, const int* in_sizes, int n_in,
                              void* d_out, int out_size, void* d_ws, size_t ws_size,
                              hipStream_t stream) {
    const float* hidden = (const float*)d_in[0];
    const int*   amask  = (const int*)d_in[1];
    const int*   pos    = (const int*)d_in[2];
    const float* wqkv   = (const float*)d_in[3];
    const float* wout   = (const float*)d_in[4];
    const float* n1w    = (const float*)d_in[5];
    const float* n2w    = (const float*)d_in[6];
    const float* rsin   = (const float*)d_in[7];
    const float* rcos   = (const float*)d_in[8];
    float* out0 = (float*)d_out;
    float* out1 = out0 + (size_t)ROWS * D_MODEL;

    char* ws = (char*)d_ws;
    ushort_t* x_bf    = (ushort_t*)ws;  ws += (size_t)ROWS * D_MODEL * 2;
    ushort_t* wqkv_t  = (ushort_t*)ws;  ws += (size_t)QKV_N * D_MODEL * 2;
    ushort_t* wout_t  = (ushort_t*)ws;  ws += (size_t)D_MODEL * D_MODEL * 2;
    ushort_t* qkv     = (ushort_t*)ws;  ws += (size_t)ROWS * QKV_N * 2;
    ushort_t* qrot    = (ushort_t*)ws;  ws += (size_t)NB * NH * SEQ * HD * 2;
    ushort_t* krot    = (ushort_t*)ws;  ws += (size_t)NB * NKV * SEQ * HD * 2;
    ushort_t* vt      = (ushort_t*)ws;  ws += (size_t)NB * NKV * HD * SEQ * 2;
    ushort_t* attn    = (ushort_t*)ws;  ws += (size_t)ROWS * D_MODEL * 2;

    k_rmsnorm_bf16<<<ROWS, 256, 0, stream>>>(hidden, n1w, x_bf);
    k_transpose_cvt<<<dim3(QKV_N / 32, D_MODEL / 32), 256, 0, stream>>>(wqkv, wqkv_t, D_MODEL, QKV_N);
    k_transpose_cvt<<<dim3(D_MODEL / 32, D_MODEL / 32), 256, 0, stream>>>(wout, wout_t, D_MODEL, D_MODEL);
    k_gemm<0><<<dim3(QKV_N / 128, ROWS / 128), 256, 0, stream>>>(x_bf, wqkv_t, qkv, nullptr, ROWS, QKV_N, D_MODEL);
    k_rope<<<ROWS * 20 / 4, 256, 0, stream>>>(qkv, pos, rsin, rcos, qrot, krot);
    k_vtrans<<<dim3(SEQ / 32, HD / 32, NB * NKV), 256, 0, stream>>>(qkv, vt);
    k_attn<<<(SEQ / 64) * 32, 256, 0, stream>>>(qrot, krot, vt, amask, attn);
    k_gemm<1><<<dim3(D_MODEL / 128, ROWS / 128), 256, 0, stream>>>(attn, wout_t, out0, hidden, ROWS, D_MODEL, D_MODEL);
    k_rmsnorm_f32<<<ROWS, 256, 0, stream>>>(out0, n2w, out1);
}